// Round 8
// baseline (1425.126 us; speedup 1.0000x reference)
//
#include <hip/hip_runtime.h>

#define T_LEN 4096

__device__ __forceinline__ float frcp(float x)  { return __builtin_amdgcn_rcpf(x); }
__device__ __forceinline__ float fexp2(float x) { return __builtin_amdgcn_exp2f(x); }

template <int CTRL>
__device__ __forceinline__ float mdpp(float x) {
  return __int_as_float(__builtin_amdgcn_mov_dpp(__float_as_int(x), CTRL, 0xF, 0xF, true));
}
template <int CTRL>
__device__ __forceinline__ float dpp_add(float x) {  // x + dpp(x)
  return x + mdpp<CTRL>(x);
}
__device__ __forceinline__ float bperm(int idx_bytes, float x) {
  return __int_as_float(__builtin_amdgcn_ds_bpermute(idx_bytes, __float_as_int(x)));
}
// tanh(a) where X = 2*log2e*a  (robust at +-inf)
__device__ __forceinline__ float tanh_pre(float X) {
  return fmaf(-2.0f, frcp(1.0f + fexp2(X)), 1.0f);
}

// 16-wide in-row rotated dot: res = seed + sum_m W[m] * v[(j-m)&15].
// Written as plain fmaf(mov_dpp(v)) chains so GCNDPPCombine can fold each
// gather+MAC into ONE v_fmac_f32_dpp (VOP2 row_ror) -- no standalone movs,
// no gather registers. Two 8-deep chains for FMA-latency overlap.
#define DOT16R(res, W, v, seed) do {                                   \
    float _a = fmaf((v), W[0], (seed));                                \
    float _b = mdpp<0x128>(v) * W[8];                                  \
    _a = fmaf(mdpp<0x121>(v), W[1],  _a);                              \
    _b = fmaf(mdpp<0x129>(v), W[9],  _b);                              \
    _a = fmaf(mdpp<0x122>(v), W[2],  _a);                              \
    _b = fmaf(mdpp<0x12A>(v), W[10], _b);                              \
    _a = fmaf(mdpp<0x123>(v), W[3],  _a);                              \
    _b = fmaf(mdpp<0x12B>(v), W[11], _b);                              \
    _a = fmaf(mdpp<0x124>(v), W[4],  _a);                              \
    _b = fmaf(mdpp<0x12C>(v), W[12], _b);                              \
    _a = fmaf(mdpp<0x125>(v), W[5],  _a);                              \
    _b = fmaf(mdpp<0x12D>(v), W[13], _b);                              \
    _a = fmaf(mdpp<0x126>(v), W[6],  _a);                              \
    _b = fmaf(mdpp<0x12E>(v), W[14], _b);                              \
    _a = fmaf(mdpp<0x127>(v), W[7],  _a);                              \
    _b = fmaf(mdpp<0x12F>(v), W[15], _b);                              \
    res = _a + _b;                                                     \
  } while (0)

// ONE chain per wave (512 waves), 64 lanes: j = l&15, u = l>>4 (row).
//  y[j], s1[j], s2[j], f[j] row-duplicated x4.
//  g: lane owns rows h*8 + 2*(j&3) + {0,1}, h = (j&12)+u; einsum d-reduce =
//  quad_perm VALU reduce; e[h]->e[j] = ONE ds_bpermute, f scheduled under it.
__global__ __launch_bounds__(64, 1) void disc_kernel(
    const float* __restrict__ ts, const float* __restrict__ ys,
    const float* __restrict__ iW1, const float* __restrict__ ib1,
    const float* __restrict__ iW2, const float* __restrict__ ib2,
    const float* __restrict__ vW1, const float* __restrict__ vb1,
    const float* __restrict__ vW2, const float* __restrict__ vb2,
    const float* __restrict__ cW1, const float* __restrict__ cb1,
    const float* __restrict__ cW2, const float* __restrict__ cb2,
    const float* __restrict__ rW, const float* __restrict__ rb,
    float* __restrict__ out)
{
  const int blk = blockIdx.x;
  const int l   = threadIdx.x;
  const int j   = l & 15;
  const int u   = l >> 4;
  const int qd  = j & 3;
  const int h   = (j & 12) + u;

  __shared__ float sbuf[16];
  __shared__ float ybq[16];
  __shared__ __align__(16) float xbuf[1024];  // 2 bufs x 64 steps x 8

  const float* __restrict__ ysc = ys + (size_t)blk * (T_LEN * 8);

  const float NL2E = -1.4426950408889634f;                 // -log2(e)
  const float TSW  = 2.0f * 1.4426950408889634f * 0.909f;  // L2 weight scale
  const float TSB  = 2.0f * 1.4426950408889634f;           // L2 bias scale
  const float NLN2 = -0.6931471805599453f;                 // -ln 2

  // ---- weights, slot-rotated for row_ror gathers (scalar layout) ----
  float WV[16], WC[16], FW[16], GW0[16], GW1[16];
#pragma unroll
  for (int m = 0; m < 16; ++m) {
    const int k = (j - m) & 15;
    WV[m] = NL2E * vW1[j * 17 + 1 + k];
    WC[m] = NL2E * cW1[j * 17 + 1 + k];
    FW[m] = TSW * vW2[j * 16 + k];
    GW0[m] = TSW * cW2[(h * 8 + 2 * qd) * 16 + k];
    GW1[m] = TSW * cW2[(h * 8 + 2 * qd + 1) * 16 + k];
  }
  const float wv_t = NL2E * vW1[j * 17];
  const float bv   = NL2E * vb1[j];
  const float wc_t = NL2E * cW1[j * 17];
  const float bc   = NL2E * cb1[j];
  const float fbv  = TSB * vb2[j];
  const float gb0  = TSB * cb2[h * 8 + 2 * qd];
  const float gb1  = TSB * cb2[h * 8 + 2 * qd + 1];

  // bpermute byte-index: src lane holds e[j] after quad-reduce
  const int bpidx = (16 * qd + (j & 12) + u) << 2;

  const float t0 = ts[0];

  // ---- init y0 = iMLP([t0, x0]) (cold; same-wave LDS is ordered) ----
  float y_own;
  {
    float hid = ib1[j] + iW1[j * 9] * t0;
#pragma unroll
    for (int d = 0; d < 8; ++d) hid = fmaf(iW1[j * 9 + 1 + d], ysc[d], hid);
    sbuf[j] = fmaxf(hid, 0.0f);              // rows dup-write identical values
    float y0 = ib2[j];
#pragma unroll
    for (int k = 0; k < 16; ++k) y0 = fmaf(iW2[j * 16 + k], sbuf[k], y0);
    y_own = y0;
  }
  // readout t0
  ybq[j] = y_own;
  if (l == 0) {
    float o = rb[0];
#pragma unroll
    for (int k = 0; k < 16; ++k) o = fmaf(rW[k], ybq[k], o);
    out[2 * blk] = o;
  }

  // ---- dx staging: lane l stages dx row l of chunk 0 ----
  {
    const int r0 = min(l, T_LEN - 1), r1 = min(l + 1, T_LEN - 1);
    const float4 a0 = *(const float4*)(ysc + r0 * 8);
    const float4 a1 = *(const float4*)(ysc + r0 * 8 + 4);
    const float4 b0 = *(const float4*)(ysc + r1 * 8);
    const float4 b1 = *(const float4*)(ysc + r1 * 8 + 4);
    float4 d0, d1;
    d0.x = b0.x - a0.x; d0.y = b0.y - a0.y; d0.z = b0.z - a0.z; d0.w = b0.w - a0.w;
    d1.x = b1.x - a1.x; d1.y = b1.y - a1.y; d1.z = b1.z - a1.z; d1.w = b1.w - a1.w;
    *(float4*)(xbuf + l * 8)     = d0;
    *(float4*)(xbuf + l * 8 + 4) = d1;
  }

  float t = t0;
  for (int c = 0; c < 64; ++c) {
    // prefetch next chunk's rows into registers (clamped)
    float4 pa0, pa1, pb0, pb1;
    {
      const int base = (c + 1 < 64 ? (c + 1) * 64 : c * 64);
      const int r0 = min(base + l, T_LEN - 1), r1 = min(base + l + 1, T_LEN - 1);
      pa0 = *(const float4*)(ysc + r0 * 8);
      pa1 = *(const float4*)(ysc + r0 * 8 + 4);
      pb0 = *(const float4*)(ysc + r1 * 8);
      pb1 = *(const float4*)(ysc + r1 * 8 + 4);
    }
    const float* __restrict__ xb = xbuf + (c & 1) * 512;
    const int nsteps = min(64, (T_LEN - 1) - c * 64);
    for (int js = 0; js < nsteps; ++js) {
      // this lane's 2 dx components (d = 2qd, 2qd+1); read early, used late
      const float2 dx2 = *(const float2*)(xb + js * 8 + 2 * qd);

      // ---- L1: two rotated dots straight off y_own (fmac_dpp chains) ----
      float u1, u2;
      DOT16R(u1, WV, y_own, fmaf(wv_t, t, bv));
      DOT16R(u2, WC, y_own, fmaf(wc_t, t, bc));
      const float s1 = (u1 * NLN2) * frcp(1.0f + fexp2(u1));
      const float s2 = (u2 * NLN2) * frcp(1.0f + fexp2(u2));

      // ---- g: 2 rotated dots off s2, tanh, einsum partial ----
      float g0, g1;
      DOT16R(g0, GW0, s2, gb0);
      DOT16R(g1, GW1, s2, gb1);
      const float tg0 = tanh_pre(g0);
      const float tg1 = tanh_pre(g1);
      float pr = fmaf(tg0, dx2.x, tg1 * dx2.y);
      // quad reduce over d-pairs (VALU): all quad lanes get e[h]
      pr = dpp_add<0xB1>(pr);
      pr = dpp_add<0x4E>(pr);
      // redistribute e[h] -> e[j] (the ONE DS op); f fills its latency
      const float ej = bperm(bpidx, pr);

      // ---- f (row-duplicated), scheduled under the bpermute ----
      float fs;
      DOT16R(fs, FW, s1, fbv);
      const float fv = tanh_pre(fs);

      y_own = y_own + (fv + ej);
      t += 1.0f;
    }
    // write prefetched dx rows into the other buffer
    {
      float* w = xbuf + ((c + 1) & 1) * 512 + l * 8;
      float4 d0, d1;
      d0.x = pb0.x - pa0.x; d0.y = pb0.y - pa0.y; d0.z = pb0.z - pa0.z; d0.w = pb0.w - pa0.w;
      d1.x = pb1.x - pa1.x; d1.y = pb1.y - pa1.y; d1.z = pb1.z - pa1.z; d1.w = pb1.w - pa1.w;
      *(float4*)(w)     = d0;
      *(float4*)(w + 4) = d1;
    }
  }

  // ---- readout t1 ----
  ybq[j] = y_own;
  if (l == 0) {
    float o = rb[0];
#pragma unroll
    for (int k = 0; k < 16; ++k) o = fmaf(rW[k], ybq[k], o);
    out[2 * blk + 1] = o;
  }
}

extern "C" void kernel_launch(void* const* d_in, const int* in_sizes, int n_in,
                              void* d_out, int out_size, void* d_ws, size_t ws_size,
                              hipStream_t stream) {
  (void)in_sizes; (void)n_in; (void)out_size; (void)d_ws; (void)ws_size;
  const float* ts  = (const float*)d_in[0];
  const float* ys  = (const float*)d_in[1];
  const float* iW1 = (const float*)d_in[2];
  const float* ib1 = (const float*)d_in[3];
  const float* iW2 = (const float*)d_in[4];
  const float* ib2 = (const float*)d_in[5];
  const float* vW1 = (const float*)d_in[6];
  const float* vb1 = (const float*)d_in[7];
  const float* vW2 = (const float*)d_in[8];
  const float* vb2 = (const float*)d_in[9];
  const float* cW1 = (const float*)d_in[10];
  const float* cb1 = (const float*)d_in[11];
  const float* cW2 = (const float*)d_in[12];
  const float* cb2 = (const float*)d_in[13];
  const float* rW  = (const float*)d_in[14];
  const float* rb  = (const float*)d_in[15];
  float* out = (float*)d_out;
  hipLaunchKernelGGL(disc_kernel, dim3(512), dim3(64), 0, stream,
                     ts, ys, iW1, ib1, iW2, ib2, vW1, vb1, vW2, vb2,
                     cW1, cb1, cW2, cb2, rW, rb, out);
}